// Round 1
// baseline (483.954 us; speedup 1.0000x reference)
//
#include <hip/hip_runtime.h>

// Chamfer distance, N=M=16384, D=3, f32.
// dist(i,j) = |x_i|^2 + |y_j|^2 - 2 x_i . y_j  (clamped >= 0)
//           = -2 * ( dot - 0.5|y_j|^2 - 0.5|x_i|^2 )
// min_j dist(i,j) = -2 * ( max_j (dot_j - 0.5|y_j|^2) - 0.5|x_i|^2 )
// -> inner loop is 3 FMA + 1 max per pair; owner-side constant folds out.

#define SLICES 16

// Pack (v0, v1, v2, 0.5*|v|^2) and init the min array to +inf (re-done every
// call so graph replay is deterministic).
__global__ void cd_prep(const float* __restrict__ src, float4* __restrict__ dst,
                        unsigned int* __restrict__ minArr, int n) {
    int i = blockIdx.x * blockDim.x + threadIdx.x;
    if (i < n) {
        float a = src[3 * i + 0];
        float b = src[3 * i + 1];
        float c = src[3 * i + 2];
        dst[i] = make_float4(a, b, c, 0.5f * (a * a + b * b + c * c));
        minArr[i] = 0x7f800000u;  // +inf bits
    }
}

// Owner points P (one per thread); loop over a slice of Q with wave-uniform
// (scalar-pipe) loads. Combine slice partials with uint atomicMin (valid:
// values are non-negative floats, bit order == float order).
__global__ __launch_bounds__(256) void cd_pass(const float4* __restrict__ P,
                                               const float4* __restrict__ Q,
                                               unsigned int* __restrict__ minArr,
                                               int Ltotal) {
    const int i = blockIdx.x * 256 + threadIdx.x;
    const float4 p = P[i];
    const int L = Ltotal / SLICES;
    const int j0 = blockIdx.y * L;
    float m = -INFINITY;
#pragma unroll 8
    for (int j = 0; j < L; ++j) {
        float4 q = Q[j0 + j];                 // uniform address -> s_load_dwordx4
        float acc = fmaf(p.x, q.x, -q.w);     // dot - 0.5|q|^2
        acc = fmaf(p.y, q.y, acc);
        acc = fmaf(p.z, q.z, acc);
        m = fmaxf(m, acc);
    }
    float d = fmaxf(0.0f, 2.0f * (p.w - m));  // clamped min distance over slice
    atomicMin(&minArr[i], __float_as_uint(d));
}

// Single-block final reduction: mean of minx[N] ++ miny[M].
__global__ __launch_bounds__(256) void cd_reduce(const unsigned int* __restrict__ minx,
                                                 const unsigned int* __restrict__ miny,
                                                 float* __restrict__ out, int n, int mm) {
    float s = 0.0f;
    for (int i = threadIdx.x; i < n; i += 256) s += __uint_as_float(minx[i]);
    for (int i = threadIdx.x; i < mm; i += 256) s += __uint_as_float(miny[i]);
    for (int off = 32; off >= 1; off >>= 1) s += __shfl_down(s, off, 64);
    __shared__ float wsum[4];
    int wave = threadIdx.x >> 6;
    int lane = threadIdx.x & 63;
    if (lane == 0) wsum[wave] = s;
    __syncthreads();
    if (threadIdx.x == 0) {
        float t = wsum[0] + wsum[1] + wsum[2] + wsum[3];
        out[0] = t / (float)(n + mm);
    }
}

extern "C" void kernel_launch(void* const* d_in, const int* in_sizes, int n_in,
                              void* d_out, int out_size, void* d_ws, size_t ws_size,
                              hipStream_t stream) {
    const float* x = (const float*)d_in[0];
    const float* y = (const float*)d_in[1];
    const int N = in_sizes[0] / 3;  // 16384
    const int M = in_sizes[1] / 3;  // 16384

    float4* xp = (float4*)d_ws;                   // N float4
    float4* yp = xp + N;                          // M float4
    unsigned int* minx = (unsigned int*)(yp + M); // N uint
    unsigned int* miny = minx + N;                // M uint
    float* out = (float*)d_out;

    cd_prep<<<(N + 255) / 256, 256, 0, stream>>>(x, xp, minx, N);
    cd_prep<<<(M + 255) / 256, 256, 0, stream>>>(y, yp, miny, M);

    cd_pass<<<dim3(N / 256, SLICES), 256, 0, stream>>>(xp, yp, minx, M);
    cd_pass<<<dim3(M / 256, SLICES), 256, 0, stream>>>(yp, xp, miny, N);

    cd_reduce<<<1, 256, 0, stream>>>(minx, miny, out, N, M);
}

// Round 2
// 88.830 us; speedup vs baseline: 5.4481x; 5.4481x over previous
//
#include <hip/hip_runtime.h>

// Chamfer distance, N=M=16384, D=3, f32.
// dist(i,j) = |x_i|^2 + |y_j|^2 - 2 x_i . y_j  (clamped >= 0)
//           = -2 * ( dot - 0.5|q|^2 - 0.5|p|^2 )
// min_j dist = -2 * ( max_j (dot_j - 0.5|q_j|^2) - 0.5|p|^2 )
// Inner loop: 3 FMA + 1 max per pair. T=8 owner points/thread amortize the
// q-load 8x and give 8 independent fmax chains (ILP).

#define TPB 256
#define T 8        // owner points per thread
#define SLICES 64  // q-dimension slices (parallelism)
#define LQ 256     // q's per slice = 16384 / SLICES

// Pack (v0, v1, v2, 0.5*|v|^2) and init the min array to +inf (re-done every
// call so graph replay is deterministic).
__global__ void cd_prep(const float* __restrict__ src, float4* __restrict__ dst,
                        unsigned int* __restrict__ minArr, int n) {
    int i = blockIdx.x * blockDim.x + threadIdx.x;
    if (i < n) {
        float a = src[3 * i + 0];
        float b = src[3 * i + 1];
        float c = src[3 * i + 2];
        dst[i] = make_float4(a, b, c, 0.5f * (a * a + b * b + c * c));
        minArr[i] = 0x7f800000u;  // +inf bits
    }
}

// Each block: 2048 owner points (8/thread, stride TPB for coalescing) x one
// LDS-staged Q slice of 256 points. Combine slice partials via uint atomicMin
// (valid: distances are >= 0, so float order == uint bit order).
__global__ __launch_bounds__(TPB) void cd_pass(const float4* __restrict__ P,
                                               const float4* __restrict__ Q,
                                               unsigned int* __restrict__ minArr,
                                               int Ltotal) {
    __shared__ float4 qs[LQ];
    const int j0 = blockIdx.y * LQ;
    for (int j = threadIdx.x; j < LQ; j += TPB) qs[j] = Q[j0 + j];
    __syncthreads();

    const int base = blockIdx.x * (TPB * T) + threadIdx.x;
    float4 p[T];
    float m[T];
#pragma unroll
    for (int k = 0; k < T; ++k) {
        p[k] = P[base + k * TPB];
        m[k] = -INFINITY;
    }

#pragma unroll 4
    for (int j = 0; j < LQ; ++j) {
        float4 q = qs[j];  // uniform address -> broadcast ds_read_b128
#pragma unroll
        for (int k = 0; k < T; ++k) {
            float acc = fmaf(p[k].x, q.x, -q.w);  // dot - 0.5|q|^2
            acc = fmaf(p[k].y, q.y, acc);
            acc = fmaf(p[k].z, q.z, acc);
            m[k] = fmaxf(m[k], acc);
        }
    }

#pragma unroll
    for (int k = 0; k < T; ++k) {
        float d = fmaxf(0.0f, 2.0f * (p[k].w - m[k]));
        atomicMin(&minArr[base + k * TPB], __float_as_uint(d));
    }
}

// Single-block final reduction: mean of minx[N] ++ miny[M].
__global__ __launch_bounds__(TPB) void cd_reduce(const unsigned int* __restrict__ minx,
                                                 const unsigned int* __restrict__ miny,
                                                 float* __restrict__ out, int n, int mm) {
    float s = 0.0f;
    for (int i = threadIdx.x; i < n; i += TPB) s += __uint_as_float(minx[i]);
    for (int i = threadIdx.x; i < mm; i += TPB) s += __uint_as_float(miny[i]);
    for (int off = 32; off >= 1; off >>= 1) s += __shfl_down(s, off, 64);
    __shared__ float wsum[4];
    int wave = threadIdx.x >> 6;
    int lane = threadIdx.x & 63;
    if (lane == 0) wsum[wave] = s;
    __syncthreads();
    if (threadIdx.x == 0) {
        float t = wsum[0] + wsum[1] + wsum[2] + wsum[3];
        out[0] = t / (float)(n + mm);
    }
}

extern "C" void kernel_launch(void* const* d_in, const int* in_sizes, int n_in,
                              void* d_out, int out_size, void* d_ws, size_t ws_size,
                              hipStream_t stream) {
    const float* x = (const float*)d_in[0];
    const float* y = (const float*)d_in[1];
    const int N = in_sizes[0] / 3;  // 16384
    const int M = in_sizes[1] / 3;  // 16384

    float4* xp = (float4*)d_ws;                    // N float4
    float4* yp = xp + N;                           // M float4
    unsigned int* minx = (unsigned int*)(yp + M);  // N uint
    unsigned int* miny = minx + N;                 // M uint
    float* out = (float*)d_out;

    cd_prep<<<(N + TPB - 1) / TPB, TPB, 0, stream>>>(x, xp, minx, N);
    cd_prep<<<(M + TPB - 1) / TPB, TPB, 0, stream>>>(y, yp, miny, M);

    cd_pass<<<dim3(N / (TPB * T), SLICES), TPB, 0, stream>>>(xp, yp, minx, M);
    cd_pass<<<dim3(M / (TPB * T), SLICES), TPB, 0, stream>>>(yp, xp, miny, N);

    cd_reduce<<<1, TPB, 0, stream>>>(minx, miny, out, N, M);
}

// Round 3
// 52.686 us; speedup vs baseline: 9.1856x; 1.6860x over previous
//
#include <hip/hip_runtime.h>

// Chamfer distance, N=M=16384, D=3, f32.
// dist(i,j) = |x_i|^2 + |y_j|^2 - 2 x_i . y_j  (clamped >= 0)
// min_j dist = -2 * ( max_j (dot_j - 0.5|q_j|^2) - 0.5|p|^2 )
// Inner loop: 3 FMA + 1 max per pair (the VALU floor — no fp32 MFMA on CDNA4).
// T=8 owner points/thread amortize the q broadcast 8x and give 8 independent
// fmax chains (ILP). Both directions fused in one kernel (blockIdx.z) so the
// machine sees 2048 blocks = 8 blocks/CU = 8 waves/SIMD.

#define TPB 256
#define T 8         // owner points per thread
#define SLICES 128  // q-dimension slices per direction
#define LQ 128      // q's per slice = 16384 / SLICES (2 KB LDS: all ds_read
                    // offsets fit the 16-bit immediate -> no loop addr math)

// Pack (v0, v1, v2, 0.5*|v|^2) for both arrays and init min arrays to +inf
// (re-done every call so graph replay is deterministic).
__global__ void cd_prep(const float* __restrict__ x, const float* __restrict__ y,
                        float4* __restrict__ xp, float4* __restrict__ yp,
                        unsigned int* __restrict__ minx, unsigned int* __restrict__ miny,
                        int n, int mm) {
    int i = blockIdx.x * blockDim.x + threadIdx.x;
    const float* src = (i < n) ? x : y;
    int k = (i < n) ? i : i - n;
    if (i < n + mm) {
        float a = src[3 * k + 0];
        float b = src[3 * k + 1];
        float c = src[3 * k + 2];
        float4 v = make_float4(a, b, c, 0.5f * (a * a + b * b + c * c));
        if (i < n) { xp[k] = v; minx[k] = 0x7f800000u; }
        else       { yp[k] = v; miny[k] = 0x7f800000u; }
    }
}

// blockIdx.z = direction (0: x owners vs y, 1: y owners vs x).
// Each block: TPB*T owner points (stride TPB, coalesced) x one LDS-staged
// Q slice of LQ points. Slice partials combined via uint atomicMin (valid:
// distances >= 0, so float order == uint bit order).
__global__ __launch_bounds__(TPB) void cd_pass_dual(const float4* __restrict__ xp,
                                                    const float4* __restrict__ yp,
                                                    unsigned int* __restrict__ minx,
                                                    unsigned int* __restrict__ miny) {
    const float4* P;
    const float4* Q;
    unsigned int* out;
    if (blockIdx.z == 0) { P = xp; Q = yp; out = minx; }
    else                 { P = yp; Q = xp; out = miny; }

    __shared__ float4 qs[LQ];
    const int j0 = blockIdx.y * LQ;
    for (int j = threadIdx.x; j < LQ; j += TPB) qs[j] = Q[j0 + j];
    __syncthreads();

    const int base = blockIdx.x * (TPB * T) + threadIdx.x;
    float4 p[T];
    float m[T];
#pragma unroll
    for (int k = 0; k < T; ++k) {
        p[k] = P[base + k * TPB];
        m[k] = -INFINITY;
    }

#pragma unroll 16
    for (int j = 0; j < LQ; ++j) {
        float4 q = qs[j];  // uniform address -> broadcast ds_read_b128
#pragma unroll
        for (int k = 0; k < T; ++k) {
            float acc = fmaf(p[k].x, q.x, -q.w);  // dot - 0.5|q|^2
            acc = fmaf(p[k].y, q.y, acc);
            acc = fmaf(p[k].z, q.z, acc);
            m[k] = fmaxf(m[k], acc);
        }
    }

#pragma unroll
    for (int k = 0; k < T; ++k) {
        float d = fmaxf(0.0f, 2.0f * (p[k].w - m[k]));
        atomicMin(&out[base + k * TPB], __float_as_uint(d));
    }
}

// Single-block final reduction: mean of minx[N] ++ miny[M] (N, M mult of 4096).
__global__ __launch_bounds__(1024) void cd_reduce(const uint4* __restrict__ minx,
                                                  const uint4* __restrict__ miny,
                                                  float* __restrict__ out, int n, int mm) {
    float s = 0.0f;
    for (int i = threadIdx.x; i < n / 4; i += 1024) {
        uint4 v = minx[i];
        s += __uint_as_float(v.x) + __uint_as_float(v.y) +
             __uint_as_float(v.z) + __uint_as_float(v.w);
    }
    for (int i = threadIdx.x; i < mm / 4; i += 1024) {
        uint4 v = miny[i];
        s += __uint_as_float(v.x) + __uint_as_float(v.y) +
             __uint_as_float(v.z) + __uint_as_float(v.w);
    }
    for (int off = 32; off >= 1; off >>= 1) s += __shfl_down(s, off, 64);
    __shared__ float wsum[16];
    int wave = threadIdx.x >> 6;
    int lane = threadIdx.x & 63;
    if (lane == 0) wsum[wave] = s;
    __syncthreads();
    if (threadIdx.x == 0) {
        float t = 0.0f;
        for (int w = 0; w < 16; ++w) t += wsum[w];
        out[0] = t / (float)(n + mm);
    }
}

extern "C" void kernel_launch(void* const* d_in, const int* in_sizes, int n_in,
                              void* d_out, int out_size, void* d_ws, size_t ws_size,
                              hipStream_t stream) {
    const float* x = (const float*)d_in[0];
    const float* y = (const float*)d_in[1];
    const int N = in_sizes[0] / 3;  // 16384
    const int M = in_sizes[1] / 3;  // 16384

    float4* xp = (float4*)d_ws;                    // N float4
    float4* yp = xp + N;                           // M float4
    unsigned int* minx = (unsigned int*)(yp + M);  // N uint
    unsigned int* miny = minx + N;                 // M uint
    float* out = (float*)d_out;

    cd_prep<<<(N + M + TPB - 1) / TPB, TPB, 0, stream>>>(x, y, xp, yp, minx, miny, N, M);

    // grid: (owner blocks, slices, direction)
    cd_pass_dual<<<dim3(N / (TPB * T), SLICES, 2), TPB, 0, stream>>>(xp, yp, minx, miny);

    cd_reduce<<<1, 1024, 0, stream>>>((const uint4*)minx, (const uint4*)miny, out, N, M);
}